// Round 8
// baseline (287.276 us; speedup 1.0000x reference)
//
#include <hip/hip_runtime.h>
#include <math.h>

// ---------------------------------------------------------------------------
// STPGCN forward. fp32 I/O, bf16 MFMA internal, fp32 accumulate.
// B=4 T=12 V=512 C=64 d=8 TS=3 P=12 L=4, BETA=2.
// R25 = champion R17 with agg+combine fused into ONE layer_kernel (grid 192
// = 48bt x 4 j-tiles), keeping champion MFMA density (32 MFMA/wave/barrier):
// phase1 = 128j x 64c GEMM over K=1536 (3 k-segs contiguous in Abf row),
// K-step 128, per-k fp32 accs (static idx), ev-weights in fp32 epilogue
// (G's bf16 rounding removed -> strictly tighter); then champion combine's
// GEMM2/GLU/GFS phases verbatim from LDS. Deletes per layer: G 18.8MB
// round-trip, combine's serial k-reduce, 1 dispatch boundary (~3us, R24),
// and the 8.3% of agg FLOPs that made never-consumed G slices.
// Ablation ledger: R22 full-2x => W=131.6us addressable, F~107us harness.
// R24 tail-3x => W_tail=17.6us (4 kernels+gaps) => ~3us/dispatch overhead.
// Laws: (1) no cross-block sync; (2) phases stay wide; (3) one lever/round;
// (4) fusion must not lose grid width (R18); (5) traffic alone not a lever;
// (9) keep >=32 MFMA/wave per barrier phase (R20: 8 -> +28.5; R23: 16 ->
// +12.4); (7) staging mechanics not the lever (R21).
// ---------------------------------------------------------------------------

typedef unsigned short u16;
typedef __attribute__((ext_vector_type(8))) short short8;
typedef __attribute__((ext_vector_type(4))) float f32x4;
typedef __attribute__((ext_vector_type(8))) unsigned short u16x8;
typedef __attribute__((ext_vector_type(4))) unsigned short u16x4;

#define MFMA16(a, b, c) __builtin_amdgcn_mfma_f32_16x16x32_bf16((a), (b), (c), 0, 0, 0)

__device__ __forceinline__ float b2f(u16 u) {
  union { unsigned int i; float f; } x; x.i = ((unsigned int)u) << 16; return x.f;
}
__device__ __forceinline__ u16 f2b(float f) {
  union { float f; unsigned int i; } x; x.f = f;
  unsigned int r = x.i + 0x7FFFu + ((x.i >> 16) & 1u);
  return (u16)(r >> 16);
}
__device__ __forceinline__ void ld8f(const float* __restrict__ p, float* f) {
  f32x4 a = *(const f32x4*)p;
  f32x4 b = *(const f32x4*)(p + 4);
  #pragma unroll
  for (int i = 0; i < 4; ++i) { f[i] = a[i]; f[4 + i] = b[i]; }
}
__device__ __forceinline__ float gcf(const float* e, const float* __restrict__ mu,
                                     const float* __restrict__ sg) {
  float s = 0.f;
  #pragma unroll
  for (int i = 0; i < 8; ++i) {
    float dm = e[i] - mu[i];
    s += dm * dm * sg[i] * sg[i];
  }
  return -0.5f * s;
}
__device__ __forceinline__ float sigm(float v) { return 1.0f / (1.0f + expf(-v)); }

// ---------------------------------------------------------------------------
// prep (unchanged champion)
// ---------------------------------------------------------------------------
__global__ __launch_bounds__(256) void prep_kernel(
    const float* __restrict__ x, const float* __restrict__ sape,
    const float* __restrict__ tape, const float* __restrict__ srpe,
    const float* __restrict__ trpe, const float* __restrict__ Wi,
    const float* __restrict__ bi, const float* __restrict__ gmu,
    const float* __restrict__ gsg, const float* __restrict__ Wg,
    const float* __restrict__ bg, const float* __restrict__ Wsp,
    const float* __restrict__ Wtp, const float* __restrict__ fsw,
    const float* __restrict__ mask,
    const float* __restrict__ g1w, const float* __restrict__ gw,
    const float* __restrict__ ow,
    u16* __restrict__ hT0, u16* __restrict__ Abf,
    float* __restrict__ spb, float* __restrict__ tpb,
    u16* __restrict__ fswT, u16* __restrict__ WgT, float* __restrict__ ev,
    u16* __restrict__ g1wB, u16* __restrict__ gwB, u16* __restrict__ owB) {
  const int tid = threadIdx.x;
  int bid = blockIdx.x;

  if (bid < 768) {  // h0 -> hT0[b][t][c][i]
    int gid = bid * 256 + tid;                 // 196608 items
    int i8 = gid & 63, c = (gid >> 6) & 63, bt = gid >> 12;
    float xv[8];
    ld8f(&x[bt * 512 + i8 * 8], xv);
    float wic = Wi[c], bic = bi[c];
    u16x8 hv;
    #pragma unroll
    for (int ii = 0; ii < 8; ++ii) hv[ii] = f2b(xv[ii] * wic + bic);
    *(u16x8*)&hT0[gid * 8] = hv;
    return;
  }
  bid -= 768;
  if (bid < 1024) {  // Abf: thread per (j,i); expbase for 4 l's, then x mask
    int gid = bid * 256 + tid;                 // 262144
    int i = gid & 511, j = gid >> 9;
    float fi[8], fj[8], fr[8];
    ld8f(sape + i * 8, fi);
    ld8f(sape + j * 8, fj);
    ld8f(srpe + ((size_t)i * 512 + j) * 8, fr);
    u16 eb[4];
    #pragma unroll
    for (int l = 0; l < 4; ++l) {
      const float* mub = gmu + l * 48;
      const float* sgb = gsg + l * 48;
      float s = gcf(fi, mub + 0, sgb + 0)
              + gcf(fj, mub + 8, sgb + 8)
              + gcf(fr, mub + 32, sgb + 32);
      eb[l] = f2b(expf(s));
    }
    #pragma unroll
    for (int b = 0; b < 4; ++b)
      #pragma unroll
      for (int k = 0; k < 3; ++k) {
        float mv = mask[((size_t)(b * 512 + j)) * 1536 + k * 512 + i];
        u16 m = (mv != 0.f) ? (u16)0xFFFFu : (u16)0;
        #pragma unroll
        for (int l = 0; l < 4; ++l)
          Abf[((size_t)((l * 4 + b) * 512 + j)) * 1536 + k * 512 + i] = eb[l] & m;
      }
    return;
  }
  bid -= 1024;
  if (bid < 1024) {  // spb[l][j][o] = sape[j]·Wsp[l][:,o]
    int gid = bid * 256 + tid;                 // 262144
    int o = gid & 127, j = (gid >> 7) & 511, l = gid >> 16;
    float s = 0.f;
    #pragma unroll
    for (int dd = 0; dd < 8; ++dd)
      s += sape[j * 8 + dd] * Wsp[(l * 8 + dd) * 128 + o];
    spb[gid] = s;
    return;
  }
  bid -= 1024;
  if (bid < 96) {  // tpb[l][bt][o] = bg[l][o] + tape[bt]·Wtp[l][:,o]
    int gid = bid * 256 + tid;                 // 24576
    int o = gid & 127, bt = (gid >> 7) % 48, l = gid / 6144;
    float s = bg[l * 128 + o];
    #pragma unroll
    for (int dd = 0; dd < 8; ++dd)
      s += tape[bt * 8 + dd] * Wtp[(l * 8 + dd) * 128 + o];
    tpb[gid] = s;
    return;
  }
  bid -= 96;
  if (bid < 768) {  // fswT[l][o][t*64+c] = fs_w[l][o][c][t]
    int gid = bid * 256 + tid;                 // 196608
    int kidx = gid % 768, rest = gid / 768;
    int o = rest & 63, l = rest >> 6;
    int c = kidx & 63, tt = kidx >> 6;
    fswT[gid] = f2b(fsw[((l * 64 + o) * 64 + c) * 12 + tt]);
    return;
  }
  bid -= 768;
  if (bid < 128) {  // WgT[l][o][c] = Wg[l][c][o]
    int gid = bid * 256 + tid;                 // 32768
    int c = gid & 63, o = (gid >> 6) & 127, l = gid >> 13;
    WgT[gid] = f2b(Wg[(l * 64 + c) * 128 + o]);
    return;
  }
  bid -= 128;
  if (bid < 3) {  // ev[l][bt][k]
    int gid = bid * 256 + tid;
    if (gid < 576) {
      int k = gid % 3, t = (gid / 3) % 12, b = (gid / 36) % 4, l = gid / 144;
      const float* mub = gmu + l * 48;
      const float* sgb = gsg + l * 48;
      float e2[8], e3[8], e5[8];
      ld8f(tape + (b * 12 + t) * 8, e2);
      int tp = t + k - 2;
      if (tp >= 0) ld8f(tape + (b * 12 + tp) * 8, e3);
      else {
        #pragma unroll
        for (int ii = 0; ii < 8; ++ii) e3[ii] = 0.f;
      }
      ld8f(trpe + k * 8, e5);
      float s = gcf(e2, mub + 16, sgb + 16)
              + gcf(e3, mub + 24, sgb + 24)
              + gcf(e5, mub + 40, sgb + 40);
      ev[gid] = expf(s);
    }
    return;
  }
  bid -= 3;
  if (bid < 128) {  // g1wB
    int gid = bid * 256 + tid;
    g1wB[gid] = f2b(g1w[gid]);
    return;
  }
  bid -= 128;
  if (bid < 512) {  // gwB
    int gid = bid * 256 + tid;
    gwB[gid] = f2b(gw[gid]);
    return;
  }
  bid -= 512;
  {  // owB
    int gid = bid * 256 + tid;
    if (gid < 3072) owB[gid] = f2b(ow[gid]);
  }
}

// ---------------------------------------------------------------------------
// layer: one kernel per layer = agg + combine fused. grid 192 = bt(48) x mt(4).
// Phase 1: Cagg_k = sum_i Abf[b,j,k*512+i] * hT[b,t+k-2,c,i]; K-step 128,
//   per-k fp32 acc (static index via unrolled kseg loop), 32 MFMA/wave/phase.
//   tp<0 k-segments skipped (zeros_x semantics).
// Epilogue 1: aggL[j][c] = bf16(sum_k ev_k * acc_k)  (fp32, no G rounding).
// Phase 2: g = WgT x aggL (K=64) + spb/tpb + GLU -> hTout + hL.
// Phase 3: GFS partial -> ypt.
// LDS pool 52KB: phase1 As[128][136]+Bs[64][136]; later aggL/hL stride 72.
// ---------------------------------------------------------------------------
__global__ __launch_bounds__(256) void layer_kernel(
    const u16* __restrict__ Abfl, const u16* __restrict__ hT,
    const float* __restrict__ evl, const u16* __restrict__ WgTl,
    const float* __restrict__ spbl, const float* __restrict__ tpbl,
    const u16* __restrict__ fswTl,
    u16* __restrict__ hTout, u16* __restrict__ yptl) {
  __shared__ u16 pool[26112];   // 52,224 B
  const int tid = threadIdx.x, wid = tid >> 6, lane = tid & 63;
  const int l16 = lane & 15, quad = lane >> 4;
  const int mt = blockIdx.x & 3;
  const int bt = blockIdx.x >> 2;
  const int b = bt / 12, t = bt - b * 12;
  const int wm = wid >> 1, wn = wid & 1;

  const u16* Arow0 = Abfl + ((size_t)(b * 512 + mt * 128)) * 1536;

  f32x4 acc[3][4][2] = {};

  #pragma unroll
  for (int kseg = 0; kseg < 3; ++kseg) {
    const int tp = t + kseg - 2;
    if (tp < 0) continue;                      // block-uniform branch
    const u16* Hbase = hT + ((size_t)((b * 12 + tp) * 64)) * 512;
    for (int sub = 0; sub < 4; ++sub) {
      const int K0 = kseg * 512 + sub * 128;   // col in Abf row
      const int i0 = sub * 128;                // col in hT row
      #pragma unroll
      for (int s = 0; s < 8; ++s) {            // A: 128 rows x 128 cols
        int idx = s * 256 + tid;
        int r = idx >> 4, ch = (idx & 15) * 8;
        *(u16x8*)&pool[r * 136 + ch] =
            *(const u16x8*)&Arow0[(size_t)r * 1536 + K0 + ch];
      }
      #pragma unroll
      for (int s = 0; s < 4; ++s) {            // B: 64 rows x 128 cols
        int idx = s * 256 + tid;
        int c = idx >> 4, ch = (idx & 15) * 8;
        *(u16x8*)&pool[17408 + c * 136 + ch] =
            *(const u16x8*)&Hbase[(size_t)c * 512 + i0 + ch];
      }
      __syncthreads();
      #pragma unroll
      for (int ks = 0; ks < 4; ++ks) {
        short8 af[4], bfv[2];
        #pragma unroll
        for (int mb = 0; mb < 4; ++mb)
          af[mb] = *(const short8*)&pool[(wm * 64 + mb * 16 + l16) * 136 +
                                         ks * 32 + quad * 8];
        #pragma unroll
        for (int nb = 0; nb < 2; ++nb)
          bfv[nb] = *(const short8*)&pool[17408 + (wn * 32 + nb * 16 + l16) * 136 +
                                          ks * 32 + quad * 8];
        #pragma unroll
        for (int mb = 0; mb < 4; ++mb)
          #pragma unroll
          for (int nb = 0; nb < 2; ++nb)
            acc[kseg][mb][nb] = MFMA16(af[mb], bfv[nb], acc[kseg][mb][nb]);
      }
      __syncthreads();
    }
  }

  // epilogue 1: fp32 k-weighted combine -> aggL (stride 72) bf16
  {
    const float e0 = evl[bt * 3 + 0];
    const float e1 = evl[bt * 3 + 1];
    const float e2 = evl[bt * 3 + 2];
    #pragma unroll
    for (int mb = 0; mb < 4; ++mb)
      #pragma unroll
      for (int nb = 0; nb < 2; ++nb) {
        int n = wn * 32 + nb * 16 + l16;
        #pragma unroll
        for (int r = 0; r < 4; ++r) {
          int m = wm * 64 + mb * 16 + quad * 4 + r;
          float v = e0 * acc[0][mb][nb][r] + e1 * acc[1][mb][nb][r] +
                    e2 * acc[2][mb][nb][r];
          pool[m * 72 + n] = f2b(v);
        }
      }
  }
  __syncthreads();

  // phase 2: g[o,j] = sum_c WgT[o][c]*agg[j][c]  (champion combine verbatim)
  f32x4 acc2[8][2] = {};
  #pragma unroll
  for (int ks = 0; ks < 2; ++ks) {
    short8 bf2[2];
    #pragma unroll
    for (int nb = 0; nb < 2; ++nb)
      bf2[nb] = *(const short8*)&pool[(wid * 32 + nb * 16 + l16) * 72 +
                                      ks * 32 + quad * 8];
    #pragma unroll
    for (int mb = 0; mb < 8; ++mb) {
      short8 a = *(const short8*)&WgTl[(mb * 16 + l16) * 64 + ks * 32 + quad * 8];
      acc2[mb][0] = MFMA16(a, bf2[0], acc2[mb][0]);
      acc2[mb][1] = MFMA16(a, bf2[1], acc2[mb][1]);
    }
  }

  // epilogue 2: + spb + tpb, GLU, write hTout + hL (pool+9216, stride 72)
  #pragma unroll
  for (int mb = 0; mb < 4; ++mb) {
    int ob = mb * 16 + quad * 4;
    #pragma unroll
    for (int nb = 0; nb < 2; ++nb) {
      int jl = wid * 32 + nb * 16 + l16;
      int jg = mt * 128 + jl;
      f32x4 spl = *(const f32x4*)&spbl[jg * 128 + ob];
      f32x4 spr = *(const f32x4*)&spbl[jg * 128 + 64 + ob];
      f32x4 tpl = *(const f32x4*)&tpbl[bt * 128 + ob];
      f32x4 tpr = *(const f32x4*)&tpbl[bt * 128 + 64 + ob];
      #pragma unroll
      for (int r = 0; r < 4; ++r) {
        float vl = acc2[mb][nb][r] + spl[r] + tpl[r];
        float vr = acc2[mb + 4][nb][r] + spr[r] + tpr[r];
        u16 hb = f2b(vl * sigm(vr));
        hTout[((size_t)(bt * 64 + ob + r)) * 512 + jg] = hb;
        pool[9216 + jl * 72 + ob + r] = hb;
      }
    }
  }
  __syncthreads();

  // phase 3: GFS partial y_t[o][j] = sum_c fswT[o][t*64+c] * h[j][c] -> ypt
  f32x4 accY[4][2] = {};
  #pragma unroll
  for (int ks = 0; ks < 2; ++ks) {
    short8 bfv[2];
    #pragma unroll
    for (int nb = 0; nb < 2; ++nb)
      bfv[nb] = *(const short8*)&pool[9216 + (wid * 32 + nb * 16 + l16) * 72 +
                                      ks * 32 + quad * 8];
    #pragma unroll
    for (int mb = 0; mb < 4; ++mb) {
      short8 a = *(const short8*)&fswTl[(mb * 16 + l16) * 768 + t * 64 +
                                        ks * 32 + quad * 8];
      accY[mb][0] = MFMA16(a, bfv[0], accY[mb][0]);
      accY[mb][1] = MFMA16(a, bfv[1], accY[mb][1]);
    }
  }
  #pragma unroll
  for (int mb = 0; mb < 4; ++mb)
    #pragma unroll
    for (int nb = 0; nb < 2; ++nb) {
      int j = mt * 128 + wid * 32 + nb * 16 + l16;
      #pragma unroll
      for (int r = 0; r < 4; ++r) {
        int o = mb * 16 + quad * 4 + r;
        yptl[((size_t)(bt * 64 + o)) * 512 + j] = f2b(accY[mb][nb][r]);
      }
    }
}

// ---------------------------------------------------------------------------
// reduce: yB[l][b][o][v] = bf16(sum_t ypt(bf16) + fsb). grid 512.
// ---------------------------------------------------------------------------
__global__ __launch_bounds__(256) void reduce_kernel(
    const u16* __restrict__ ypt, const float* __restrict__ fsb,
    u16* __restrict__ yB) {
  int gid = blockIdx.x * 256 + threadIdx.x;    // 131072
  int j4 = gid & 127, o = (gid >> 7) & 63, b = (gid >> 13) & 3, l = gid >> 15;
  const u16* base = &ypt[(size_t)l * 1572864 +
                         ((size_t)((b * 12) * 64 + o)) * 512 + j4 * 4];
  float fb = fsb[l * 64 + o];
  f32x4 s = {fb, fb, fb, fb};
  #pragma unroll
  for (int t = 0; t < 12; ++t) {
    u16x4 v = *(const u16x4*)&base[(size_t)t * 32768];
    #pragma unroll
    for (int ii = 0; ii < 4; ++ii) s[ii] += b2f(v[ii]);
  }
  u16x4 pk;
  #pragma unroll
  for (int ii = 0; ii < 4; ++ii) pk[ii] = f2b(s[ii]);
  *(u16x4*)&yB[((size_t)((l * 4 + b) * 64 + o)) * 512 + j4 * 4] = pk;
}

// ---------------------------------------------------------------------------
// glu1cat
// ---------------------------------------------------------------------------
__global__ __launch_bounds__(256) void glu1cat_kernel(
    const u16* __restrict__ yB, const u16* __restrict__ g1wB,
    const float* __restrict__ g1b, u16* __restrict__ catB) {
  __shared__ u16 yL[128][72];
  const int tid = threadIdx.x, wid = tid >> 6, lane = tid & 63;
  const int l16 = lane & 15, quad = lane >> 4;
  const int l = blockIdx.x >> 4;
  const int b = (blockIdx.x >> 2) & 3;
  const int v0 = (blockIdx.x & 3) * 128;

  {
    int o = tid & 63, sv = tid >> 6;
    const u16* src = &yB[((size_t)((l * 4 + b) * 64 + o)) * 512 + v0 + sv * 32];
    u16x8 p0 = *(const u16x8*)&src[0];
    u16x8 p1 = *(const u16x8*)&src[8];
    u16x8 p2 = *(const u16x8*)&src[16];
    u16x8 p3 = *(const u16x8*)&src[24];
    #pragma unroll
    for (int ii = 0; ii < 8; ++ii) {
      yL[sv * 32 + ii][o] = p0[ii];
      yL[sv * 32 + 8 + ii][o] = p1[ii];
      yL[sv * 32 + 16 + ii][o] = p2[ii];
      yL[sv * 32 + 24 + ii][o] = p3[ii];
    }
  }
  __syncthreads();

  f32x4 acc[2][8] = {};
  #pragma unroll
  for (int ks = 0; ks < 2; ++ks) {
    short8 a0 = *(const short8*)&g1wB[l * 8192 + (wid * 16 + l16) * 64 +
                                      ks * 32 + quad * 8];
    short8 a1 = *(const short8*)&g1wB[l * 8192 + (64 + wid * 16 + l16) * 64 +
                                      ks * 32 + quad * 8];
    #pragma unroll
    for (int nb = 0; nb < 8; ++nb) {
      short8 bf = *(const short8*)&yL[nb * 16 + l16][ks * 32 + quad * 8];
      acc[0][nb] = MFMA16(a0, bf, acc[0][nb]);
      acc[1][nb] = MFMA16(a1, bf, acc[1][nb]);
    }
  }
  #pragma unroll
  for (int nb = 0; nb < 8; ++nb) {
    int v = v0 + nb * 16 + l16;
    int oc = wid * 16 + quad * 4;
    u16x4 pk;
    #pragma unroll
    for (int r = 0; r < 4; ++r) {
      float zl = acc[0][nb][r] + g1b[l * 128 + oc + r];
      float zr = acc[1][nb][r] + g1b[l * 128 + 64 + oc + r];
      pk[r] = f2b(zl * sigm(zr));
    }
    *(u16x4*)&catB[((size_t)(b * 512 + v)) * 256 + l * 64 + oc] = pk;
  }
}

// ---------------------------------------------------------------------------
// gout
// ---------------------------------------------------------------------------
__global__ __launch_bounds__(256) void gout_kernel(
    const u16* __restrict__ catB, const u16* __restrict__ gwB,
    const float* __restrict__ gb, u16* __restrict__ sB) {
  __shared__ u16 cL[64][264];
  const int tid = threadIdx.x, wid = tid >> 6, lane = tid & 63;
  const int l16 = lane & 15, quad = lane >> 4;
  const int wm = wid >> 1, wn = wid & 1;
  const int b = blockIdx.x >> 6;
  const int v0 = ((blockIdx.x >> 3) & 7) * 64;
  const int cc0 = (blockIdx.x & 7) * 32;

  {
    int v = tid >> 2, seg = (tid & 3) * 64;
    const u16* src = &catB[((size_t)(b * 512 + v0 + v)) * 256 + seg];
    #pragma unroll
    for (int s = 0; s < 8; ++s)
      *(u16x8*)&cL[v][seg + s * 8] = *(const u16x8*)&src[s * 8];
  }
  __syncthreads();

  f32x4 acc[2][2] = {};
  #pragma unroll
  for (int ks = 0; ks < 8; ++ks) {
    short8 aL = *(const short8*)&gwB[(cc0 + wm * 16 + l16) * 256 +
                                     ks * 32 + quad * 8];
    short8 aH = *(const short8*)&gwB[(256 + cc0 + wm * 16 + l16) * 256 +
                                     ks * 32 + quad * 8];
    #pragma unroll
    for (int nb = 0; nb < 2; ++nb) {
      short8 bf = *(const short8*)&cL[wn * 32 + nb * 16 + l16][ks * 32 + quad * 8];
      acc[0][nb] = MFMA16(aL, bf, acc[0][nb]);
      acc[1][nb] = MFMA16(aH, bf, acc[1][nb]);
    }
  }
  #pragma unroll
  for (int nb = 0; nb < 2; ++nb) {
    int v = v0 + wn * 32 + nb * 16 + l16;
    int cc = cc0 + wm * 16 + quad * 4;
    u16x4 pk;
    #pragma unroll
    for (int r = 0; r < 4; ++r) {
      float zl = acc[0][nb][r] + gb[cc + r];
      float zr = acc[1][nb][r] + gb[256 + cc + r];
      pk[r] = f2b(zl * sigm(zr));
    }
    *(u16x4*)&sB[((size_t)(b * 512 + v)) * 256 + cc] = pk;
  }
}

// ---------------------------------------------------------------------------
// head
// ---------------------------------------------------------------------------
__global__ __launch_bounds__(256) void head_kernel(
    const u16* __restrict__ sB, const u16* __restrict__ owB,
    const float* __restrict__ obv, float* __restrict__ out) {
  const int tid = threadIdx.x, wid = tid >> 6, lane = tid & 63;
  const int l16 = lane & 15, quad = lane >> 4;
  const int b = blockIdx.x >> 3;
  const int v0 = (blockIdx.x & 7) * 64;

  f32x4 acc = {};
  #pragma unroll
  for (int ks = 0; ks < 8; ++ks) {
    short8 a;
    if (l16 < 12) a = *(const short8*)&owB[l16 * 256 + ks * 32 + quad * 8];
    else {
      #pragma unroll
      for (int ii = 0; ii < 8; ++ii) a[ii] = 0;
    }
    short8 bf = *(const short8*)&sB[((size_t)(b * 512 + v0 + wid * 16 + l16)) * 256 +
                                    ks * 32 + quad * 8];
    acc = MFMA16(a, bf, acc);
  }
  #pragma unroll
  for (int r = 0; r < 4; ++r) {
    int p = quad * 4 + r;
    if (p < 12)
      out[(b * 12 + p) * 512 + v0 + wid * 16 + l16] = acc[r] + obv[p];
  }
}

// ---------------------------------------------------------------------------
extern "C" void kernel_launch(void* const* d_in, const int* in_sizes, int n_in,
                              void* d_out, int out_size, void* d_ws, size_t ws_size,
                              hipStream_t stream) {
  const float* x    = (const float*)d_in[0];
  const float* sape = (const float*)d_in[1];
  const float* tape = (const float*)d_in[2];
  const float* srpe = (const float*)d_in[3];
  const float* trpe = (const float*)d_in[4];
  const float* mask = (const float*)d_in[7];
  const float* Wi   = (const float*)d_in[8];
  const float* bi   = (const float*)d_in[9];
  const float* gmu  = (const float*)d_in[10];
  const float* gsg  = (const float*)d_in[11];
  const float* Wg   = (const float*)d_in[12];
  const float* bg   = (const float*)d_in[13];
  const float* Wsp  = (const float*)d_in[14];
  const float* Wtp  = (const float*)d_in[15];
  const float* fsw  = (const float*)d_in[16];
  const float* fsb  = (const float*)d_in[17];
  const float* g1w  = (const float*)d_in[18];
  const float* g1b  = (const float*)d_in[19];
  const float* gow  = (const float*)d_in[20];
  const float* gob  = (const float*)d_in[21];
  const float* ow   = (const float*)d_in[22];
  const float* obv  = (const float*)d_in[23];

  char* w = (char*)d_ws;
  u16*   hT_a = (u16*)(w + 0);            // 3,145,728 B
  u16*   hT_b = (u16*)(w + 3145728);      // 3,145,728 B
  u16*   Abf  = (u16*)(w + 6291456);      // 25,165,824 B (4 layers)
  u16*   fswT = (u16*)(w + 40894464);     // 393,216 B
  u16*   WgT  = (u16*)(w + 41287680);     // 65,536 B
  u16*   g1wB = (u16*)(w + 41353216);     // 65,536 B
  u16*   gwB  = (u16*)(w + 41418752);     // 262,144 B
  u16*   owB  = (u16*)(w + 41680896);     // 8,192 B
  float* spb  = (float*)(w + 41689088);   // 1,048,576 B
  float* tpb  = (float*)(w + 42737664);   // 98,304 B
  float* ev   = (float*)(w + 42835968);   // 16,384 B
  u16*   ypt  = (u16*)(w + 42852352);     // 12,582,912 B (4 x 1,572,864 u16)
  u16*   yB   = (u16*)(w + 55435264);     // 2,097,152 B
  u16*   catB = (u16*)(w + 57532416);     // 1,048,576 B
  u16*   sB   = (u16*)(w + 58580992);     // 1,048,576 B

  prep_kernel<<<4463, 256, 0, stream>>>(x, sape, tape, srpe, trpe, Wi, bi, gmu, gsg,
                                        Wg, bg, Wsp, Wtp, fsw, mask, g1w, gow, ow,
                                        hT_a, Abf, spb, tpb, fswT, WgT, ev,
                                        g1wB, gwB, owB);
  u16* hin = hT_a;
  u16* hout = hT_b;
  for (int l = 0; l < 4; ++l) {
    layer_kernel<<<192, 256, 0, stream>>>(Abf + (size_t)l * 3145728, hin,
                                          ev + l * 144, WgT + l * 8192,
                                          spb + l * 65536, tpb + l * 6144,
                                          fswT + l * 49152, hout,
                                          ypt + (size_t)l * 1572864);
    u16* tmp = hin; hin = hout; hout = tmp;
  }
  reduce_kernel<<<512, 256, 0, stream>>>(ypt, fsb, yB);
  glu1cat_kernel<<<64, 256, 0, stream>>>(yB, g1wB, g1b, catB);
  gout_kernel<<<256, 256, 0, stream>>>(catB, gwB, gob, sB);
  head_kernel<<<32, 256, 0, stream>>>(sB, owB, obv, (float*)d_out);
}